// Round 4
// baseline (69.921 us; speedup 1.0000x reference)
//
#include <hip/hip_runtime.h>
#include <math.h>

// Problem constants (reference: pos [64,1024,3] fp32, rad=0.15)
#define TN     64
#define NP     1024
#define RADIUS 0.15f
#define MIN_D  (2.0f * RADIUS)
#define R2     (MIN_D * MIN_D)

#define BLOCK  512                 // 8 waves per block
#define WAVES  (BLOCK / 64)
#define SPLIT  8                   // blocks per timestep -> 512 blocks = 2/CU
#define GI     16                  // i-rows register-tiled per wave-group
#define NBLK   (TN * SPLIT)        // 512 blocks
#define PPT    (NP / BLOCK)        // 2 points handled per thread in the sort phase
#define NCH    (NP / 64)           // 16 chunks of 64 original-index-consecutive pts

// x-axis bins: width 1/3.3 = 0.30303 > MIN_D (0.3), so colliding pairs are
// always in same-or-adjacent bins; pairs >=2 bins apart have dx > 0.30302
// even under fp rounding of the bin index (margin 3e-3 in x vs error ~5e-6).
// Clamping only merges outer bins -> strictly conservative. Pruning is exact.
#define NB     40
#define XMIN   (-6.0f)
#define INVW   3.3f

// Pinned d^2 association: identical instruction-level rounding everywhere.
__device__ __forceinline__ float dist2(float dx, float dy, float dz) {
    return __builtin_fmaf(dx, dx, __builtin_fmaf(dy, dy, dz * dz));
}

__launch_bounds__(BLOCK, 4)   // 4 waves/EU -> 2 blocks/CU, VGPR cap 128
__global__ void collide_kernel(const float* __restrict__ pos,
                               float* __restrict__ partial) {
    __shared__ float         shs[NP * 3];        // bin-sorted xyz (interleaved)
    __shared__ unsigned char sbin[NP];           // bin id per sorted point
    __shared__ unsigned int  chunkcnt[NCH * NB]; // [chunk][bin] counts
    __shared__ unsigned int  chunkoff[NCH * NB]; // [chunk][bin] exclusive offsets
    __shared__ unsigned int  hist[NB];           // per-bin totals
    __shared__ unsigned int  S[NB + 1];          // exclusive bin starts; S[NB]=1024

    const int t     = blockIdx.x / SPLIT;
    const int split = blockIdx.x % SPLIT;
    const int tid   = threadIdx.x;
    const int lane  = tid & 63;
    const int wave  = tid >> 6;

    // ---- load 2 points/thread to registers; compute bins (deterministic) ----
    const float* pt = pos + (size_t)t * NP * 3;
    float px[PPT], py[PPT], pz[PPT];
    int   bq[PPT];
    #pragma unroll
    for (int q = 0; q < PPT; ++q) {
        const int p = tid + q * BLOCK;           // chunk = q*8 + wave, lane-ordered
        px[q] = pt[3 * p + 0];
        py[q] = pt[3 * p + 1];
        pz[q] = pt[3 * p + 2];
        int b = (int)((px[q] - XMIN) * INVW);
        bq[q] = b < 0 ? 0 : (b > NB - 1 ? NB - 1 : b);
    }
    for (int i = tid; i < NCH * NB; i += BLOCK) chunkcnt[i] = 0u;
    __syncthreads();

    // ---- within-chunk same-bin prefix + totals via shfl (NO atomics) ----
    // Chunk c = q*WAVES + wave holds original indices [c*64, c*64+64) on lanes
    // 0..63 in order. pre = # same-bin lanes below me; tot = # same-bin in chunk.
    int pre[PPT];
    #pragma unroll
    for (int q = 0; q < PPT; ++q) {
        int p = 0, tot = 0;
        for (int s = 0; s < 64; ++s) {           // uniform loop, all lanes active
            const int bs = __shfl(bq[q], s);
            const bool eq = (bs == bq[q]);
            tot += eq ? 1 : 0;
            p   += (eq && s < lane) ? 1 : 0;
        }
        pre[q] = p;
        if (p == tot - 1)                        // unique last same-bin lane
            chunkcnt[(q * WAVES + wave) * NB + bq[q]] = (unsigned int)tot;
    }
    __syncthreads();

    // ---- per-bin serial scan over chunks: offsets + bin totals ----
    if (tid < NB) {
        unsigned int run = 0;
        #pragma unroll
        for (int c = 0; c < NCH; ++c) {
            const unsigned int v = chunkcnt[c * NB + tid];
            chunkoff[c * NB + tid] = run;
            run += v;
        }
        hist[tid] = run;
    }
    __syncthreads();

    // ---- exclusive scan of bin totals (first wave, shfl) ----
    if (tid < 64) {
        unsigned int incl = (tid < NB) ? hist[tid] : 0u;
        #pragma unroll
        for (int d = 1; d < 64; d <<= 1) {
            const unsigned int y = __shfl_up(incl, d, 64);
            if (lane >= d) incl += y;
        }
        if (tid < NB) S[tid + 1] = incl;
        if (tid == 0) S[0] = 0u;
    }
    __syncthreads();

    // ---- scatter: stable (bin, original-index) sort, bijective by construction ----
    #pragma unroll
    for (int q = 0; q < PPT; ++q) {
        const int c = q * WAVES + wave;
        const unsigned int dst = S[bq[q]] + chunkoff[c * NB + bq[q]]
                               + (unsigned int)pre[q];
        shs[3 * dst + 0] = px[q];
        shs[3 * dst + 1] = py[q];
        shs[3 * dst + 2] = pz[q];
        sbin[dst] = (unsigned char)bq[q];
    }
    __syncthreads();

    // ---- per-wave group sweep with adjacent-bin cutoff (unchanged) ----
    unsigned int cnt  = 0;
    float        loss = 0.0f;
    {
        const int g = wave * SPLIT + split;   // bijective over 64 groups/timestep
        const int b = g * GI;

        float xi[GI], yi[GI], zi[GI];
        #pragma unroll
        for (int k = 0; k < GI; ++k) {        // same-address reads: LDS broadcast
            xi[k] = shs[3 * (b + k) + 0];
            yi[k] = shs[3 * (b + k) + 1];
            zi[k] = shs[3 * (b + k) + 2];
        }
        // Opaque barrier: pins the 48-value i-tile into VGPRs (prevents LDS
        // rematerialization; observed failure mode: ~56 lane-ops/pair).
        #pragma unroll
        for (int k = 0; k < GI; ++k)
            asm volatile("" : "+v"(xi[k]), "+v"(yi[k]), "+v"(zi[k]));

        // j-range cutoff: sbin non-decreasing; all pairs for this tile lie in
        // j < end of bin(last_i)+1.
        const int bb   = (int)sbin[b + GI - 1];
        const int jend = (int)S[(bb + 2 <= NB) ? (bb + 2) : NB];

        // head: in-tile pairs, one lane per j (lanes 0..14)
        if (lane < GI - 1) {
            const int j = b + 1 + lane;
            const float xj = shs[3 * j], yj = shs[3 * j + 1], zj = shs[3 * j + 2];
            #pragma unroll
            for (int k = 0; k < GI; ++k) {
                if (k <= lane) {                       // i = b+k < j
                    const float d2 = dist2(xi[k] - xj, yi[k] - yj, zi[k] - zj);
                    if (d2 < R2) {
                        cnt++;
                        const float pen = MIN_D - __builtin_amdgcn_sqrtf(d2);
                        loss += pen * pen;
                    }
                }
            }
        }

        // tail: j in [b+GI, jend), 64-lane stride
        for (int j = b + GI + lane; j < jend; j += 64) {
            const float xj = shs[3 * j], yj = shs[3 * j + 1], zj = shs[3 * j + 2];
            #pragma unroll
            for (int k = 0; k < GI; ++k) {
                const float d2 = dist2(xi[k] - xj, yi[k] - yj, zi[k] - zj);
                const bool hit = d2 < R2;
                cnt += hit ? 1u : 0u;                  // v_cmp + v_addc, no branch
                if (hit) {                             // rare (~0.25%)
                    const float pen = MIN_D - __builtin_amdgcn_sqrtf(d2);
                    loss += pen * pen;
                }
            }
        }
    }

    // ---- reduction: wave shuffle, then cross-wave via LDS (fp32) ----
    float fcnt = (float)cnt;
    #pragma unroll
    for (int off = 32; off > 0; off >>= 1) {
        fcnt += __shfl_down(fcnt, off);
        loss += __shfl_down(loss, off);
    }
    __shared__ float cs[WAVES], ls[WAVES];
    if (lane == 0) { cs[wave] = fcnt; ls[wave] = loss; }
    __syncthreads();
    if (tid == 0) {
        float c = 0.0f, l = 0.0f;
        #pragma unroll
        for (int w = 0; w < WAVES; ++w) { c += cs[w]; l += ls[w]; }
        partial[2 * blockIdx.x + 0] = c;   // unconditional store: no init needed
        partial[2 * blockIdx.x + 1] = l;
    }
}

__global__ void finalize_kernel(const float* __restrict__ partial,
                                float* __restrict__ out) {
    const int lane = threadIdx.x;          // 64 threads: single wave, no barrier
    float c = 0.0f, l = 0.0f;
    #pragma unroll
    for (int i = 0; i < NBLK / 64; ++i) {  // 8 float2 per lane
        const float2 p = ((const float2*)partial)[lane + i * 64];
        c += p.x;
        l += p.y;
    }
    #pragma unroll
    for (int off = 32; off > 0; off >>= 1) {
        c += __shfl_down(c, off);
        l += __shfl_down(l, off);
    }
    if (lane == 0) {
        out[0] = c;   // harness reads float32; count exact (< 2^24)
        out[1] = l;
    }
}

extern "C" void kernel_launch(void* const* d_in, const int* in_sizes, int n_in,
                              void* d_out, int out_size, void* d_ws, size_t ws_size,
                              hipStream_t stream) {
    const float* pos     = (const float*)d_in[0];
    float*       partial = (float*)d_ws;
    float*       out     = (float*)d_out;

    collide_kernel<<<NBLK, BLOCK, 0, stream>>>(pos, partial);
    finalize_kernel<<<1, 64, 0, stream>>>(partial, out);
}

// Round 5
// 63.415 us; speedup vs baseline: 1.1026x; 1.1026x over previous
//
#include <hip/hip_runtime.h>
#include <math.h>

// Problem constants (reference: pos [64,1024,3] fp32, rad=0.15)
#define TN     64
#define NP     1024
#define RADIUS 0.15f
#define MIN_D  (2.0f * RADIUS)
#define R2     (MIN_D * MIN_D)

#define BLOCK  512                 // 8 waves per block
#define WAVES  (BLOCK / 64)
#define SPLIT  8                   // blocks per timestep -> 512 blocks = 2/CU
#define GI     16                  // i-rows register-tiled per wave-group
#define NBLK   (TN * SPLIT)        // 512 blocks
#define PPT    (NP / BLOCK)        // 2 points handled per thread in the sort phase
#define NCH    (NP / 64)           // 16 chunks of 64 original-index-consecutive pts

// x-axis bins: width 1/3.3 = 0.30303 > MIN_D (0.3), so colliding pairs are
// always in same-or-adjacent bins; pairs >=2 bins apart have dx > 0.30302
// even under fp rounding of the bin index (margin 3e-3 in x vs error ~5e-6).
// Clamping only merges outer bins -> strictly conservative. Pruning is exact.
#define NB     40
#define XMIN   (-6.0f)
#define INVW   3.3f

// Pinned d^2 association: identical instruction-level rounding everywhere.
__device__ __forceinline__ float dist2(float dx, float dy, float dz) {
    return __builtin_fmaf(dx, dx, __builtin_fmaf(dy, dy, dz * dz));
}

__launch_bounds__(BLOCK, 4)   // 4 waves/EU -> 2 blocks/CU, VGPR cap 128
__global__ void collide_kernel(const float* __restrict__ pos,
                               float* __restrict__ partial) {
    __shared__ float         shs[NP * 3];        // bin-sorted xyz (interleaved)
    __shared__ unsigned char sbin[NP];           // bin id per sorted point
    __shared__ unsigned int  chunkcnt[NCH * NB]; // [chunk][bin] counts
    __shared__ unsigned int  chunkoff[NCH * NB]; // [chunk][bin] exclusive offsets
    __shared__ unsigned int  hist[NB];           // per-bin totals
    __shared__ unsigned int  S[NB + 1];          // exclusive bin starts; S[NB]=1024

    const int t     = blockIdx.x / SPLIT;
    const int split = blockIdx.x % SPLIT;
    const int tid   = threadIdx.x;
    const int lane  = tid & 63;
    const int wave  = tid >> 6;

    // ---- load 2 points/thread to registers; compute bins (deterministic) ----
    const float* pt = pos + (size_t)t * NP * 3;
    float px[PPT], py[PPT], pz[PPT];
    int   bq[PPT];
    #pragma unroll
    for (int q = 0; q < PPT; ++q) {
        const int p = tid + q * BLOCK;           // chunk = q*8 + wave, lane-ordered
        px[q] = pt[3 * p + 0];
        py[q] = pt[3 * p + 1];
        pz[q] = pt[3 * p + 2];
        int b = (int)((px[q] - XMIN) * INVW);
        bq[q] = b < 0 ? 0 : (b > NB - 1 ? NB - 1 : b);
    }
    for (int i = tid; i < NCH * NB; i += BLOCK) chunkcnt[i] = 0u;
    __syncthreads();

    // ---- within-chunk same-bin rank via ballot match-any (NO atomics) ----
    // Chunk c = q*WAVES + wave holds original indices [c*64, c*64+64) on lanes
    // 0..63 in order. 6 ballots (NB=40 < 2^6) build the mask of same-bin lanes;
    // result bit-identical to a serial stable rank: pre = same-bin lanes below,
    // tot = same-bin lanes in chunk. Deterministic by construction.
    int pre[PPT];
    #pragma unroll
    for (int q = 0; q < PPT; ++q) {
        unsigned long long m = ~0ull;
        #pragma unroll
        for (int bit = 0; bit < 6; ++bit) {
            const unsigned long long bb = __ballot((bq[q] >> bit) & 1);
            m &= ((bq[q] >> bit) & 1) ? bb : ~bb;
        }
        const int tot = __popcll(m);
        const int p   = __popcll(m & ((1ull << lane) - 1ull));
        pre[q] = p;
        if (p == tot - 1)                        // unique last same-bin lane
            chunkcnt[(q * WAVES + wave) * NB + bq[q]] = (unsigned int)tot;
    }
    __syncthreads();

    // ---- per-bin serial scan over chunks: offsets + bin totals ----
    if (tid < NB) {
        unsigned int run = 0;
        #pragma unroll
        for (int c = 0; c < NCH; ++c) {
            const unsigned int v = chunkcnt[c * NB + tid];
            chunkoff[c * NB + tid] = run;
            run += v;
        }
        hist[tid] = run;
    }
    __syncthreads();

    // ---- exclusive scan of bin totals (first wave, shfl) ----
    if (tid < 64) {
        unsigned int incl = (tid < NB) ? hist[tid] : 0u;
        #pragma unroll
        for (int d = 1; d < 64; d <<= 1) {
            const unsigned int y = __shfl_up(incl, d, 64);
            if (lane >= d) incl += y;
        }
        if (tid < NB) S[tid + 1] = incl;
        if (tid == 0) S[0] = 0u;
    }
    __syncthreads();

    // ---- scatter: stable (bin, original-index) sort, bijective by construction ----
    #pragma unroll
    for (int q = 0; q < PPT; ++q) {
        const int c = q * WAVES + wave;
        const unsigned int dst = S[bq[q]] + chunkoff[c * NB + bq[q]]
                               + (unsigned int)pre[q];
        shs[3 * dst + 0] = px[q];
        shs[3 * dst + 1] = py[q];
        shs[3 * dst + 2] = pz[q];
        sbin[dst] = (unsigned char)bq[q];
    }
    __syncthreads();

    // ---- per-wave group sweep with adjacent-bin cutoff (unchanged) ----
    unsigned int cnt  = 0;
    float        loss = 0.0f;
    {
        const int g = wave * SPLIT + split;   // bijective over 64 groups/timestep
        const int b = g * GI;

        float xi[GI], yi[GI], zi[GI];
        #pragma unroll
        for (int k = 0; k < GI; ++k) {        // same-address reads: LDS broadcast
            xi[k] = shs[3 * (b + k) + 0];
            yi[k] = shs[3 * (b + k) + 1];
            zi[k] = shs[3 * (b + k) + 2];
        }
        // Opaque barrier: pins the 48-value i-tile into VGPRs (prevents LDS
        // rematerialization; observed failure mode: ~56 lane-ops/pair).
        #pragma unroll
        for (int k = 0; k < GI; ++k)
            asm volatile("" : "+v"(xi[k]), "+v"(yi[k]), "+v"(zi[k]));

        // j-range cutoff: sbin non-decreasing; all pairs for this tile lie in
        // j < end of bin(last_i)+1.
        const int bb   = (int)sbin[b + GI - 1];
        const int jend = (int)S[(bb + 2 <= NB) ? (bb + 2) : NB];

        // head: in-tile pairs, one lane per j (lanes 0..14)
        if (lane < GI - 1) {
            const int j = b + 1 + lane;
            const float xj = shs[3 * j], yj = shs[3 * j + 1], zj = shs[3 * j + 2];
            #pragma unroll
            for (int k = 0; k < GI; ++k) {
                if (k <= lane) {                       // i = b+k < j
                    const float d2 = dist2(xi[k] - xj, yi[k] - yj, zi[k] - zj);
                    if (d2 < R2) {
                        cnt++;
                        const float pen = MIN_D - __builtin_amdgcn_sqrtf(d2);
                        loss += pen * pen;
                    }
                }
            }
        }

        // tail: j in [b+GI, jend), 64-lane stride
        for (int j = b + GI + lane; j < jend; j += 64) {
            const float xj = shs[3 * j], yj = shs[3 * j + 1], zj = shs[3 * j + 2];
            #pragma unroll
            for (int k = 0; k < GI; ++k) {
                const float d2 = dist2(xi[k] - xj, yi[k] - yj, zi[k] - zj);
                const bool hit = d2 < R2;
                cnt += hit ? 1u : 0u;                  // v_cmp + v_addc, no branch
                if (hit) {                             // rare (~0.25%)
                    const float pen = MIN_D - __builtin_amdgcn_sqrtf(d2);
                    loss += pen * pen;
                }
            }
        }
    }

    // ---- reduction: wave shuffle, then cross-wave via LDS (fp32) ----
    float fcnt = (float)cnt;
    #pragma unroll
    for (int off = 32; off > 0; off >>= 1) {
        fcnt += __shfl_down(fcnt, off);
        loss += __shfl_down(loss, off);
    }
    __shared__ float cs[WAVES], ls[WAVES];
    if (lane == 0) { cs[wave] = fcnt; ls[wave] = loss; }
    __syncthreads();
    if (tid == 0) {
        float c = 0.0f, l = 0.0f;
        #pragma unroll
        for (int w = 0; w < WAVES; ++w) { c += cs[w]; l += ls[w]; }
        partial[2 * blockIdx.x + 0] = c;   // unconditional store: no init needed
        partial[2 * blockIdx.x + 1] = l;
    }
}

__global__ void finalize_kernel(const float* __restrict__ partial,
                                float* __restrict__ out) {
    const int lane = threadIdx.x;          // 64 threads: single wave, no barrier
    float c = 0.0f, l = 0.0f;
    #pragma unroll
    for (int i = 0; i < NBLK / 64; ++i) {  // 8 float2 per lane
        const float2 p = ((const float2*)partial)[lane + i * 64];
        c += p.x;
        l += p.y;
    }
    #pragma unroll
    for (int off = 32; off > 0; off >>= 1) {
        c += __shfl_down(c, off);
        l += __shfl_down(l, off);
    }
    if (lane == 0) {
        out[0] = c;   // harness reads float32; count exact (< 2^24)
        out[1] = l;
    }
}

extern "C" void kernel_launch(void* const* d_in, const int* in_sizes, int n_in,
                              void* d_out, int out_size, void* d_ws, size_t ws_size,
                              hipStream_t stream) {
    const float* pos     = (const float*)d_in[0];
    float*       partial = (float*)d_ws;
    float*       out     = (float*)d_out;

    collide_kernel<<<NBLK, BLOCK, 0, stream>>>(pos, partial);
    finalize_kernel<<<1, 64, 0, stream>>>(partial, out);
}

// Round 6
// 62.835 us; speedup vs baseline: 1.1128x; 1.0092x over previous
//
#include <hip/hip_runtime.h>
#include <math.h>

// Problem constants (reference: pos [64,1024,3] fp32, rad=0.15)
#define TN     64
#define NP     1024
#define RADIUS 0.15f
#define MIN_D  (2.0f * RADIUS)
#define R2     (MIN_D * MIN_D)

#define BLOCK  512                 // 8 waves per block
#define WAVES  (BLOCK / 64)
#define SPLIT  8                   // blocks per timestep -> 512 blocks = 2/CU
#define GI     16                  // i-rows register-tiled per wave-group
#define NBLK   (TN * SPLIT)        // 512 blocks
#define PPT    (NP / BLOCK)        // 2 points handled per thread in the sort phase
#define NCH    (NP / 64)           // 16 chunks of 64 original-index-consecutive pts

// x-axis bins: width 1/3.3 = 0.30303 > MIN_D (0.3), so colliding pairs are
// always in same-or-adjacent bins; pairs >=2 bins apart have dx > 0.30302
// even under fp rounding of the bin index (margin 3e-3 in x vs error ~5e-6).
// Clamping only merges outer bins -> strictly conservative. Pruning is exact.
#define NB     40
#define XMIN   (-6.0f)
#define INVW   3.3f

// Pinned d^2 association: identical instruction-level rounding everywhere.
__device__ __forceinline__ float dist2(float dx, float dy, float dz) {
    return __builtin_fmaf(dx, dx, __builtin_fmaf(dy, dy, dz * dz));
}

// Constant-index component select; folds to a direct register reference after
// full unroll (avoids runtime-indexed local arrays -> scratch, rule #20).
__device__ __forceinline__ float f4c(const float4& v, int c) {
    switch (c) {
        case 0:  return v.x;
        case 1:  return v.y;
        case 2:  return v.z;
        default: return v.w;
    }
}

__launch_bounds__(BLOCK, 4)   // 4 waves/EU -> 2 blocks/CU, VGPR cap 128
__global__ void collide_kernel(const float* __restrict__ pos,
                               float* __restrict__ partial) {
    __shared__ __align__(16) float shs[NP * 3];  // bin-sorted xyz (interleaved)
    __shared__ unsigned char sbin[NP];           // bin id per sorted point
    __shared__ unsigned int  chunkcnt[NCH * NB]; // [chunk][bin] counts
    __shared__ unsigned int  chunkoff[NCH * NB]; // [chunk][bin] exclusive offsets
    __shared__ unsigned int  S[NB + 1];          // exclusive bin starts; S[NB]=1024

    const int t     = blockIdx.x / SPLIT;
    const int split = blockIdx.x % SPLIT;
    const int tid   = threadIdx.x;
    const int lane  = tid & 63;
    const int wave  = tid >> 6;

    // ---- load 2 points/thread to registers; compute bins (deterministic) ----
    const float* pt = pos + (size_t)t * NP * 3;
    float px[PPT], py[PPT], pz[PPT];
    int   bq[PPT];
    #pragma unroll
    for (int q = 0; q < PPT; ++q) {
        const int p = tid + q * BLOCK;           // chunk = q*8 + wave, lane-ordered
        px[q] = pt[3 * p + 0];
        py[q] = pt[3 * p + 1];
        pz[q] = pt[3 * p + 2];
        int b = (int)((px[q] - XMIN) * INVW);
        bq[q] = b < 0 ? 0 : (b > NB - 1 ? NB - 1 : b);
    }
    for (int i = tid; i < NCH * NB; i += BLOCK) chunkcnt[i] = 0u;
    __syncthreads();

    // ---- within-chunk same-bin rank via ballot match-any (NO atomics) ----
    // Chunk c = q*WAVES + wave holds original indices [c*64, c*64+64) on lanes
    // 0..63 in order. 6 ballots (NB=40 < 2^6) build the mask of same-bin lanes;
    // result bit-identical to a serial stable rank: pre = same-bin lanes below,
    // tot = same-bin lanes in chunk. Deterministic by construction.
    int pre[PPT];
    #pragma unroll
    for (int q = 0; q < PPT; ++q) {
        unsigned long long m = ~0ull;
        #pragma unroll
        for (int bit = 0; bit < 6; ++bit) {
            const unsigned long long bb = __ballot((bq[q] >> bit) & 1);
            m &= ((bq[q] >> bit) & 1) ? bb : ~bb;
        }
        const int tot = __popcll(m);
        const int p   = __popcll(m & ((1ull << lane) - 1ull));
        pre[q] = p;
        if (p == tot - 1)                        // unique last same-bin lane
            chunkcnt[(q * WAVES + wave) * NB + bq[q]] = (unsigned int)tot;
    }
    __syncthreads();

    // ---- merged scan phase (wave 0 only, no intermediate barrier) ----
    // Per-bin serial scan over chunks (bin total kept in a register), then
    // exclusive shfl scan of bin totals. Lanes >= NB contribute 0.
    if (tid < 64) {
        unsigned int run = 0;
        if (tid < NB) {
            #pragma unroll
            for (int c = 0; c < NCH; ++c) {
                chunkoff[c * NB + tid] = run;
                run += chunkcnt[c * NB + tid];
            }
        }
        unsigned int incl = run;                 // inclusive scan of bin totals
        #pragma unroll
        for (int d = 1; d < 64; d <<= 1) {
            const unsigned int y = __shfl_up(incl, d, 64);
            if (lane >= d) incl += y;
        }
        if (tid < NB) S[tid + 1] = incl;         // lane 39 writes S[NB] = 1024
        if (tid == 0) S[0] = 0u;
    }
    __syncthreads();

    // ---- scatter: stable (bin, original-index) sort, bijective by construction ----
    #pragma unroll
    for (int q = 0; q < PPT; ++q) {
        const int c = q * WAVES + wave;
        const unsigned int dst = S[bq[q]] + chunkoff[c * NB + bq[q]]
                               + (unsigned int)pre[q];
        shs[3 * dst + 0] = px[q];
        shs[3 * dst + 1] = py[q];
        shs[3 * dst + 2] = pz[q];
        sbin[dst] = (unsigned char)bq[q];
    }
    __syncthreads();

    // ---- per-wave group sweep with adjacent-bin cutoff ----
    unsigned int cnt  = 0;
    float        loss = 0.0f;
    {
        const int g = wave * SPLIT + split;   // bijective over 64 groups/timestep
        const int b = g * GI;

        // j-range cutoff (issue tiny reads before the big i-tile load):
        // sbin non-decreasing; all pairs for this tile lie in
        // j < end of bin(last_i)+1.
        const int bb   = (int)sbin[b + GI - 1];
        const int jend = (int)S[(bb + 2 <= NB) ? (bb + 2) : NB];

        // i-tile: 48 contiguous floats at byte offset 192*g (16B-aligned) ->
        // 12x ds_read_b128 instead of 48x ds_read_b32 (LDS pipe is the
        // per-CU bottleneck; same values, same order -> numerics unchanged).
        float xi[GI], yi[GI], zi[GI];
        const float4* shs4 = (const float4*)(shs + 3 * b);
        #pragma unroll
        for (int r = 0; r < 12; ++r) {
            const float4 v = shs4[r];            // floats 4r .. 4r+3
            #pragma unroll
            for (int e = 0; e < 4; ++e) {
                const int f = 4 * r + e;         // all constants after unroll
                const int k = f / 3;
                const int c = f % 3;
                if (c == 0) xi[k] = f4c(v, e);
                else if (c == 1) yi[k] = f4c(v, e);
                else zi[k] = f4c(v, e);
            }
        }
        // Opaque barrier: pins the 48-value i-tile into VGPRs (prevents LDS
        // rematerialization; observed failure mode: ~56 lane-ops/pair).
        #pragma unroll
        for (int k = 0; k < GI; ++k)
            asm volatile("" : "+v"(xi[k]), "+v"(yi[k]), "+v"(zi[k]));

        // head: in-tile pairs, one lane per j (lanes 0..14)
        if (lane < GI - 1) {
            const int j = b + 1 + lane;
            const float xj = shs[3 * j], yj = shs[3 * j + 1], zj = shs[3 * j + 2];
            #pragma unroll
            for (int k = 0; k < GI; ++k) {
                if (k <= lane) {                       // i = b+k < j
                    const float d2 = dist2(xi[k] - xj, yi[k] - yj, zi[k] - zj);
                    if (d2 < R2) {
                        cnt++;
                        const float pen = MIN_D - __builtin_amdgcn_sqrtf(d2);
                        loss += pen * pen;
                    }
                }
            }
        }

        // tail: j in [b+GI, jend), 64-lane stride
        for (int j = b + GI + lane; j < jend; j += 64) {
            const float xj = shs[3 * j], yj = shs[3 * j + 1], zj = shs[3 * j + 2];
            #pragma unroll
            for (int k = 0; k < GI; ++k) {
                const float d2 = dist2(xi[k] - xj, yi[k] - yj, zi[k] - zj);
                const bool hit = d2 < R2;
                cnt += hit ? 1u : 0u;                  // v_cmp + v_addc, no branch
                if (hit) {                             // rare (~0.25%)
                    const float pen = MIN_D - __builtin_amdgcn_sqrtf(d2);
                    loss += pen * pen;
                }
            }
        }
    }

    // ---- reduction: wave shuffle, then cross-wave via LDS (fp32) ----
    float fcnt = (float)cnt;
    #pragma unroll
    for (int off = 32; off > 0; off >>= 1) {
        fcnt += __shfl_down(fcnt, off);
        loss += __shfl_down(loss, off);
    }
    __shared__ float cs[WAVES], ls[WAVES];
    if (lane == 0) { cs[wave] = fcnt; ls[wave] = loss; }
    __syncthreads();
    if (tid == 0) {
        float c = 0.0f, l = 0.0f;
        #pragma unroll
        for (int w = 0; w < WAVES; ++w) { c += cs[w]; l += ls[w]; }
        partial[2 * blockIdx.x + 0] = c;   // unconditional store: no init needed
        partial[2 * blockIdx.x + 1] = l;
    }
}

__global__ void finalize_kernel(const float* __restrict__ partial,
                                float* __restrict__ out) {
    const int lane = threadIdx.x;          // 64 threads: single wave, no barrier
    float c = 0.0f, l = 0.0f;
    #pragma unroll
    for (int i = 0; i < NBLK / 64; ++i) {  // 8 float2 per lane
        const float2 p = ((const float2*)partial)[lane + i * 64];
        c += p.x;
        l += p.y;
    }
    #pragma unroll
    for (int off = 32; off > 0; off >>= 1) {
        c += __shfl_down(c, off);
        l += __shfl_down(l, off);
    }
    if (lane == 0) {
        out[0] = c;   // harness reads float32; count exact (< 2^24)
        out[1] = l;
    }
}

extern "C" void kernel_launch(void* const* d_in, const int* in_sizes, int n_in,
                              void* d_out, int out_size, void* d_ws, size_t ws_size,
                              hipStream_t stream) {
    const float* pos     = (const float*)d_in[0];
    float*       partial = (float*)d_ws;
    float*       out     = (float*)d_out;

    collide_kernel<<<NBLK, BLOCK, 0, stream>>>(pos, partial);
    finalize_kernel<<<1, 64, 0, stream>>>(partial, out);
}